// Round 17
// baseline (83.650 us; speedup 1.0000x reference)
//
#include <hip/hip_runtime.h>
#include <hip/hip_bf16.h>

typedef __attribute__((ext_vector_type(8))) __bf16 bf16x8;
typedef __attribute__((ext_vector_type(4))) float f32x4;

#if __has_builtin(__builtin_amdgcn_sad_u8)
__device__ __forceinline__ unsigned sad8(unsigned a, unsigned b, unsigned acc) {
    return __builtin_amdgcn_sad_u8(a, b, acc);
}
#else
__device__ __forceinline__ unsigned sad8(unsigned a, unsigned b, unsigned acc) {
    #pragma unroll
    for (int i = 0; i < 4; ++i) {
        int xa = (a >> (8 * i)) & 255, xb = (b >> (8 * i)) & 255;
        acc += (unsigned)((xa > xb) ? (xa - xb) : (xb - xa));
    }
    return acc;
}
#endif

// ---------------------------------------------------------------------------
// prep (fallback path only): W1 [128 k][128 col] f32 -> W1t [col][k] bf16
// ---------------------------------------------------------------------------
__global__ void prep_w1_kernel(const float* __restrict__ W1,
                               __bf16* __restrict__ W1t) {
    int i = blockIdx.x * 256 + threadIdx.x;
    int c = i >> 7;
    int k = i & 127;
    W1t[i] = (__bf16)W1[k * 128 + c];
}

// ---------------------------------------------------------------------------
// Merged prep: each block recomputes the sign-sort permutation locally
// (plus-w2 columns first), writes its slice of the permuted weights.
// MFMA column j = ct*16+cc <-> rank p = cc*8+ct; H-col c = perm_inv[p].
// Block 0 also computes vv[k] = sum_c W1[k][c]*W2[c]  (rowsum is linear in
// nf: R = nf.v + const), and thread i==0 emits qs = {1/s, 0.495*s, b1.W2}
// and np.
// ---------------------------------------------------------------------------
__global__ void prep_kernel(const float* __restrict__ W1,
                            const float* __restrict__ b1,
                            const float* __restrict__ W2,
                            __bf16* __restrict__ W1pt,
                            float* __restrict__ b1p,
                            float* __restrict__ w2p,
                            float* __restrict__ vv,
                            int* __restrict__ npout,
                            float* __restrict__ qs) {
    __shared__ int perm_inv_s[128];
    __shared__ int wcnt[2];
    __shared__ float wmax[2];
    const int tid  = threadIdx.x;
    const int lane = tid & 63;
    const int w    = tid >> 6;
    bool pos = false;
    int rank = 0;
    if (tid < 128) {
        const float w2 = W2[tid];
        pos = (w2 > 0.f);
        unsigned long long bal = __ballot(pos);
        rank = __popcll(bal & ((1ull << lane) - 1ull));
        int cnt = __popcll(bal);
        float m = __builtin_fabsf(w2);
        #pragma unroll
        for (int d = 1; d < 64; d <<= 1) m = fmaxf(m, __shfl_xor(m, d, 64));
        if (lane == 0) { wcnt[w] = cnt; wmax[w] = m; }
    }
    __syncthreads();
    if (tid < 128) {
        const int npv   = wcnt[0] + wcnt[1];
        const int basep = (w == 1) ? wcnt[0] : 0;
        const int negb  = (w == 1) ? (64 - wcnt[0]) : 0;
        const int p = pos ? (basep + rank) : (npv + negb + (lane - rank));
        perm_inv_s[p] = tid;
    }
    __syncthreads();

    const int i = blockIdx.x * 256 + tid;     // 64 blocks x 256 = 16384
    const int j = i >> 7;
    const int k = i & 127;
    const int c = perm_inv_s[(j & 15) * 8 + (j >> 4)];
    W1pt[i] = (__bf16)W1[k * 128 + c];
    if (k == 0) { b1p[j] = b1[c]; w2p[j] = W2[c]; }

    if (blockIdx.x == 0 && tid < 128) {       // vv[k] = W1 row k . W2
        float dp = 0.f;
        const float* wr = W1 + tid * 128;
        #pragma unroll 8
        for (int c4 = 0; c4 < 32; ++c4) {
            f32x4 a = *(const f32x4*)(wr + c4 * 4);
            f32x4 b = *(const f32x4*)(W2 + c4 * 4);
            dp += a[0] * b[0] + a[1] * b[1] + a[2] * b[2] + a[3] * b[3];
        }
        vv[tid] = dp;
    }
    if (i == 0) {
        float mm = fmaxf(wmax[0], wmax[1]);
        float s  = (mm > 0.f) ? (6.0f * mm / 120.0f) : 1.0f;
        float cc1 = 0.f;
        for (int c4 = 0; c4 < 32; ++c4) {
            f32x4 a = *(const f32x4*)(b1 + c4 * 4);
            f32x4 b = *(const f32x4*)(W2 + c4 * 4);
            cc1 += a[0] * b[0] + a[1] * b[1] + a[2] * b[2] + a[3] * b[3];
        }
        qs[0] = 1.0f / s;
        qs[1] = 0.495f * s;
        qs[2] = cc1;
        *npout = wcnt[0] + wcnt[1];
    }
}

// ---------------------------------------------------------------------------
// Precompute, MODE-UNIFORM, one-shot (1 tile/wave), MINIMAL EPILOGUE —
// the r4 recipe: MFMA -> quantize -> store. No R, no reduction chains,
// no conditional-lane stores in mode0.
//   mode0: rawA = nf@W1[0:64]+b1 -> A1u u8 PLAIN rank order (128 B/row);
//          lane cc: 8 quantized bytes -> one int2 store. Zero shfl.
//   mode1: rawB = nf@W1[64:128]  -> A2q 2-bit (32 B/row): within-dword rank
//          j=(cc&1)*8+ct at bit 8*(j&3)+2*(j>>2)  [r12/r13-verified];
//          lane-pair merge via one shfl_xor(1); even lane stores 4 B.
// Quant: s = 6*max|w2|/120; u8 = clamp(128 + raw*|w2|/s); 2-bit code =
//        floor(clamp(2.00588 - raw*|w2|/(85 s), 0, 3)).
// ---------------------------------------------------------------------------
__global__ void precomp_kernel(const float* __restrict__ nf,
                               const float* __restrict__ b1p,
                               const float* __restrict__ w2p,
                               const __bf16* __restrict__ W1pt,
                               const float* __restrict__ qs,
                               unsigned char* __restrict__ A1u,
                               unsigned char* __restrict__ A2q,
                               int T2, int mode) {
    const int lane = threadIdx.x & 63;
    const int wid  = threadIdx.x >> 6;
    const int cc   = lane & 15;
    const int kg   = lane >> 4;
    const int g    = blockIdx.x * 4 + wid;
    if (g >= T2) return;
    const int koff = mode ? 64 : 0;

    // nf loads first (the HBM/L3 long pole)
    const float* ap = nf + ((long)g * 16 + cc) * 64 + kg * 8;
    f32x4 lo0 = *(const f32x4*)(ap);
    f32x4 hi0 = *(const f32x4*)(ap + 4);
    f32x4 lo1 = *(const f32x4*)(ap + 32);
    f32x4 hi1 = *(const f32x4*)(ap + 36);

    bf16x8 bfrag[8][2];
    #pragma unroll
    for (int ct = 0; ct < 8; ++ct) {
        const __bf16* colp = W1pt + (ct * 16 + cc) * 128 + koff + kg * 8;
        bfrag[ct][0] = *(const bf16x8*)(colp);
        bfrag[ct][1] = *(const bf16x8*)(colp + 32);
    }
    const float inv_s = qs[0];
    float bw[8], qm[8];
    #pragma unroll
    for (int ct = 0; ct < 8; ++ct) {
        const int col = ct * 16 + cc;
        const float m8 = inv_s * __builtin_fabsf(w2p[col]);
        bw[ct] = mode ? 0.f : b1p[col];
        qm[ct] = mode ? (-m8 * (1.0f / 85.0f)) : m8;
    }
    const int oddadd = (cc & 1) ? 4 : 0;

    bf16x8 a0, a1;
    #pragma unroll
    for (int j = 0; j < 4; ++j) {
        a0[j] = (__bf16)lo0[j]; a0[4 + j] = (__bf16)hi0[j];
        a1[j] = (__bf16)lo1[j]; a1[4 + j] = (__bf16)hi1[j];
    }

    f32x4 acc[8];
    #pragma unroll
    for (int ct = 0; ct < 8; ++ct) acc[ct] = (f32x4){0.f, 0.f, 0.f, 0.f};
    #pragma unroll
    for (int ct = 0; ct < 8; ++ct) {
        acc[ct] = __builtin_amdgcn_mfma_f32_16x16x32_bf16(a0, bfrag[ct][0], acc[ct], 0, 0, 0);
        acc[ct] = __builtin_amdgcn_mfma_f32_16x16x32_bf16(a1, bfrag[ct][1], acc[ct], 0, 0, 0);
    }

    #pragma unroll
    for (int r = 0; r < 4; ++r) {
        const long n = (long)g * 16 + kg * 4 + r;
        if (mode == 0) {
            unsigned ub[8];
            #pragma unroll
            for (int ct = 0; ct < 8; ++ct) {
                const float raw = acc[ct][r] + bw[ct];
                float x = fmaf(raw, qm[ct], 128.f);
                x = fminf(fmaxf(x, 1.f), 254.f);
                ub[ct] = (unsigned)(x + 0.5f);
            }
            int2 o;
            o.x = (int)(ub[0] | (ub[1] << 8) | (ub[2] << 16) | (ub[3] << 24));
            o.y = (int)(ub[4] | (ub[5] << 8) | (ub[6] << 16) | (ub[7] << 24));
            *(int2*)(A1u + n * 128 + cc * 8) = o;
        } else {
            unsigned pk = 0;
            #pragma unroll
            for (int ct = 0; ct < 8; ++ct) {
                float t = fmaf(acc[ct][r], qm[ct], 2.00588f);
                t = fminf(fmaxf(t, 0.f), 3.0f);
                pk |= ((unsigned)t) << (8 * (ct & 3) + 2 * (ct >> 2) + oddadd);
            }
            const unsigned ph = (unsigned)__shfl_xor((int)pk, 1, 64);
            const unsigned dwv = pk | ph;
            if (!(cc & 1))
                *(unsigned*)(A2q + n * 32 + (cc >> 1) * 4) = dwv;
        }
    }
}

// ---------------------------------------------------------------------------
// Rowsum kernel (separate, trivial): R = 0.505*(nf.v + const), linear in nf.
//   R1[n] = 0.505*(nf[n].v1 + b1.W2) + b2     (v1 = vv[0:64])
//   R2[n] = 0.505*(nf[n].v2)                  (v2 = vv[64:128])
// Wave handles 16 nodes (cc=node, kg=k-quarter); 2 shfl reduce over kg;
// lane<16 coalesced stores. Grid-strided 512 blocks (~3 tiles/wave).
// ---------------------------------------------------------------------------
__global__ void rsum_kernel(const float* __restrict__ nf,
                            const float* __restrict__ qs,
                            const float* __restrict__ vv,
                            const float* __restrict__ b2,
                            float* __restrict__ R1,
                            float* __restrict__ R2,
                            int T2) {
    const int lane = threadIdx.x & 63;
    const int wid  = threadIdx.x >> 6;
    const int cc   = lane & 15;
    const int kg   = lane >> 4;

    const float* v1b = vv + kg * 8;
    const f32x4 v10 = *(const f32x4*)(v1b);
    const f32x4 v11 = *(const f32x4*)(v1b + 4);
    const f32x4 v12 = *(const f32x4*)(v1b + 32);
    const f32x4 v13 = *(const f32x4*)(v1b + 36);
    const float* v2b = vv + 64 + kg * 8;
    const f32x4 v20 = *(const f32x4*)(v2b);
    const f32x4 v21 = *(const f32x4*)(v2b + 4);
    const f32x4 v22 = *(const f32x4*)(v2b + 32);
    const f32x4 v23 = *(const f32x4*)(v2b + 36);
    const float c1adj = 0.505f * qs[2] + b2[0];

    const int stride = gridDim.x * 4;
    for (int g = blockIdx.x * 4 + wid; g < T2; g += stride) {
        const float* ap = nf + ((long)g * 16 + cc) * 64 + kg * 8;
        f32x4 lo0 = *(const f32x4*)(ap);
        f32x4 hi0 = *(const f32x4*)(ap + 4);
        f32x4 lo1 = *(const f32x4*)(ap + 32);
        f32x4 hi1 = *(const f32x4*)(ap + 36);

        float d1 = 0.f, d2 = 0.f;
        #pragma unroll
        for (int j = 0; j < 4; ++j) {
            d1 = fmaf(lo0[j], v10[j], d1);
            d1 = fmaf(hi0[j], v11[j], d1);
            d1 = fmaf(lo1[j], v12[j], d1);
            d1 = fmaf(hi1[j], v13[j], d1);
            d2 = fmaf(lo0[j], v20[j], d2);
            d2 = fmaf(hi0[j], v21[j], d2);
            d2 = fmaf(lo1[j], v22[j], d2);
            d2 = fmaf(hi1[j], v23[j], d2);
        }
        d1 += __shfl_xor(d1, 16, 64);
        d1 += __shfl_xor(d1, 32, 64);
        d2 += __shfl_xor(d2, 16, 64);
        d2 += __shfl_xor(d2, 32, 64);
        if (lane < 16) {
            R1[(long)g * 16 + cc] = fmaf(0.505f, d1, c1adj);
            R2[(long)g * 16 + cc] = 0.505f * d2;
        }
    }
}

// ---------------------------------------------------------------------------
// Edge pass, one edge per lane, one-shot wave. Per-wave dst self-check
// (coalesced load + ballot): canonical -> dv=e>>4, slot=e&15, score+filler.
// Slow path (any sorted dst): binary-search slot; firstseg/lastseg/tail
// lanes write all remaining fillers.
//   A2 row: 2 int4 (32 B, 3.2 MB table -> per-XCD L2-resident)
//   plane k of dword d: x=(v>>2k)&0x03030303, y=x*85 -> A1 dword 4d+k
//   (plain A1: byte b of dword m holds rank 4m+b).
//   masks: dword m, byte b on iff rank 4m+b < np (prefix).
//   score = R1[dv] + R2[se] + 0.495*s*(2*S_plus - S_all)
// ---------------------------------------------------------------------------
__global__ void edge_kernel(const unsigned char* __restrict__ A1u,
                            const unsigned char* __restrict__ A2q,
                            const float* __restrict__ R1,
                            const float* __restrict__ R2,
                            const float* __restrict__ qs,
                            const int* __restrict__ npp,
                            const int* __restrict__ src,
                            const int* __restrict__ dst,
                            float* __restrict__ out,
                            int E, int K, int N) {
    const int lane = threadIdx.x & 63;
    const int gw   = blockIdx.x * 4 + (threadIdx.x >> 6);
    const float k0 = qs[1];
    const int np   = *npp;

    unsigned M[32];                     // wave-uniform prefix masks
    #pragma unroll
    for (int m = 0; m < 32; ++m) {
        const int t = np - 4 * m;
        M[m] = (t >= 4) ? 0xFFFFFFFFu
             : ((t <= 0) ? 0u : (0xFFFFFFFFu >> (8 * (4 - t))));
    }

    const int e = gw * 64 + lane;
    const bool act = (e < E);
    const int dvl = act ? dst[e] : 0;
    const bool okc = !act || (dvl == (e >> 4));
    const bool fast = (__ballot(okc) == ~0ull);
    if (!act) return;

    int dv, slot;
    bool firstseg = false, lastseg = false;
    if (fast) { dv = e >> 4; slot = e & 15; }
    else {
        dv = dvl;
        int lo = 0, hi = e;
        while (lo < hi) {
            int mid = (lo + hi) >> 1;
            if (dst[mid] < dv) lo = mid + 1; else hi = mid;
        }
        slot = e - lo;
        firstseg = (e == 0) || (dst[e - 1] != dv);
        lastseg  = (e + 1 >= E) || (dst[e + 1] != dv);
    }
    const int se = src[e];

    const unsigned char* bp = A2q + (long)se * 32;
    int4 q0 = *(const int4*)(bp);
    int4 q1 = *(const int4*)(bp + 16);
    const unsigned char* ap_ = A1u + (long)dv * 128;
    unsigned A[32];
    #pragma unroll
    for (int i = 0; i < 8; ++i) {
        int4 t = *(const int4*)(ap_ + i * 16);
        A[4 * i]     = (unsigned)t.x;
        A[4 * i + 1] = (unsigned)t.y;
        A[4 * i + 2] = (unsigned)t.z;
        A[4 * i + 3] = (unsigned)t.w;
    }
    const float r12 = R1[dv] + R2[se];

    unsigned B[8] = {(unsigned)q0.x, (unsigned)q0.y, (unsigned)q0.z, (unsigned)q0.w,
                     (unsigned)q1.x, (unsigned)q1.y, (unsigned)q1.z, (unsigned)q1.w};
    unsigned sall = 0, spl = 0;
    #pragma unroll
    for (int d = 0; d < 8; ++d) {
        const unsigned v = B[d];
        #pragma unroll
        for (int k = 0; k < 4; ++k) {
            unsigned x = (v >> (2 * k)) & 0x03030303u;
            unsigned y = x + (x << 2);     // x*5
            y = y + (y << 4);              // x*85  (no cross-byte carries)
            const unsigned mm = M[4 * d + k];
            const unsigned aa = A[4 * d + k];
            sall = sad8(aa, y, sall);
            spl  = sad8(aa & mm, y & mm, spl);
        }
    }

    const float score = fmaf(k0, 2.0f * (float)spl - (float)sall, r12);
    float* orow = out + (long)dv * K;
    if (fast) {
        orow[slot]      = score;
        orow[16 + slot] = -1e10f;
    } else {
        if (slot < K) orow[slot] = score;
        if (lastseg)
            for (int q = (slot + 1 < 0 ? 0 : slot + 1); q < K; ++q)
                orow[q] = -1e10f;
        if (firstseg) {
            const int prev = (e == 0) ? -1 : dst[e - 1];
            for (long nn = prev + 1; nn < dv; ++nn)
                for (int q = 0; q < K; ++q) out[nn * K + q] = -1e10f;
        }
        if (e == E - 1)
            for (long nn = (long)dv + 1; nn < N; ++nn)
                for (int q = 0; q < K; ++q) out[nn * K + q] = -1e10f;
    }
}

// ---------------------------------------------------------------------------
// Fallback (round-1 kernel) for non-special shapes / tiny ws.
// ---------------------------------------------------------------------------
__global__ void attack_kernel_f(
    const float* __restrict__ nf, const float* __restrict__ b1,
    const float* __restrict__ W2, const float* __restrict__ b2,
    const int* __restrict__ src, const int* __restrict__ dst,
    const __bf16* __restrict__ W1t, float* __restrict__ out,
    int T, int K, int DEG)
{
    const int lane = threadIdx.x & 63;
    const int wid  = threadIdx.x >> 6;
    const int row  = lane & 15;
    const int kg   = lane >> 4;

    bf16x8 bfrag[8][4];
    #pragma unroll
    for (int ct = 0; ct < 8; ++ct) {
        const __bf16* colp = W1t + (ct * 16 + row) * 128 + kg * 8;
        #pragma unroll
        for (int kk = 0; kk < 4; ++kk)
            bfrag[ct][kk] = *(const bf16x8*)(colp + kk * 32);
    }
    float b1c[8], w2c[8];
    #pragma unroll
    for (int ct = 0; ct < 8; ++ct) {
        b1c[ct] = b1[ct * 16 + row];
        w2c[ct] = W2[ct * 16 + row];
    }
    const float b2v = b2[0];

    const int wstride = gridDim.x * 4;
    for (int t = blockIdx.x * 4 + wid; t < T; t += wstride) {
        const long eb = (long)t * DEG;
        const int dv = dst[eb];
        const int sv = src[eb + row];
        bf16x8 afrag[4];
        const float* dp = nf + (long)dv * 64 + kg * 8;
        const float* sp = nf + (long)sv * 64 + kg * 8;
        #pragma unroll
        for (int kk = 0; kk < 2; ++kk) {
            f32x4 lo = *(const f32x4*)(dp + kk * 32);
            f32x4 hi = *(const f32x4*)(dp + kk * 32 + 4);
            bf16x8 a;
            #pragma unroll
            for (int j = 0; j < 4; ++j) { a[j] = (__bf16)lo[j]; a[4 + j] = (__bf16)hi[j]; }
            afrag[kk] = a;
        }
        #pragma unroll
        for (int kk = 0; kk < 2; ++kk) {
            f32x4 lo = *(const f32x4*)(sp + kk * 32);
            f32x4 hi = *(const f32x4*)(sp + kk * 32 + 4);
            bf16x8 a;
            #pragma unroll
            for (int j = 0; j < 4; ++j) { a[j] = (__bf16)lo[j]; a[4 + j] = (__bf16)hi[j]; }
            afrag[2 + kk] = a;
        }
        f32x4 acc[8];
        #pragma unroll
        for (int ct = 0; ct < 8; ++ct) acc[ct] = (f32x4){0.f, 0.f, 0.f, 0.f};
        #pragma unroll
        for (int ct = 0; ct < 8; ++ct) {
            #pragma unroll
            for (int kk = 0; kk < 4; ++kk)
                acc[ct] = __builtin_amdgcn_mfma_f32_16x16x32_bf16(
                    afrag[kk], bfrag[ct][kk], acc[ct], 0, 0, 0);
        }
        float part[4] = {0.f, 0.f, 0.f, 0.f};
        #pragma unroll
        for (int ct = 0; ct < 8; ++ct) {
            #pragma unroll
            for (int r = 0; r < 4; ++r) {
                float h = acc[ct][r] + b1c[ct];
                h = fmaxf(h, 0.01f * h);
                part[r] = fmaf(h, w2c[ct], part[r]);
            }
        }
        #pragma unroll
        for (int m = 1; m < 16; m <<= 1) {
            #pragma unroll
            for (int r = 0; r < 4; ++r)
                part[r] += __shfl_xor(part[r], m, 64);
        }
        float* orow = out + (long)dv * K;
        if (row == 0) {
            f32x4 v;
            #pragma unroll
            for (int r = 0; r < 4; ++r) v[r] = part[r] + b2v;
            *(f32x4*)(orow + kg * 4) = v;
            *(f32x4*)(orow + DEG + kg * 4) = (f32x4){-1e10f, -1e10f, -1e10f, -1e10f};
        }
    }
}

extern "C" void kernel_launch(void* const* d_in, const int* in_sizes, int n_in,
                              void* d_out, int out_size, void* d_ws, size_t ws_size,
                              hipStream_t stream) {
    const float* nf  = (const float*)d_in[0];
    const float* W1  = (const float*)d_in[1];
    const float* b1  = (const float*)d_in[2];
    const float* W2  = (const float*)d_in[3];
    const float* b2  = (const float*)d_in[4];
    const int*   src = (const int*)d_in[5];
    const int*   dst = (const int*)d_in[6];
    float* out = (float*)d_out;

    const int H    = in_sizes[2];          // 128
    const int twoD = in_sizes[1] / H;      // 128
    const int D    = twoD / 2;             // 64
    const int N    = in_sizes[0] / D;      // 100000
    const int E    = in_sizes[5];          // 1600000
    const int DEG  = E / N;                // 16
    const int K    = out_size / N;         // 32

    // ws layout
    const size_t w1_off   = 0;                 // 32 KiB (W1pt or W1t)
    const size_t qs_off   = 32768;             // 16 B
    const size_t np_off   = 32784;             // 4 B
    const size_t vv_off   = 32800;             // 512 B (v1|v2)
    const size_t b1p_off  = 33312;             // 512 B
    const size_t w2p_off  = 33824;             // 512 B
    const size_t A1_off   = 34560;             // 256-aligned
    const size_t A1_sz    = (size_t)N * 128;   // u8 table (12.8 MB)
    const size_t A2_off   = A1_off + A1_sz;
    const size_t A2_sz    = (size_t)N * 32;    // 2-bit table (3.2 MB)
    const size_t R1_off   = A2_off + A2_sz;
    const size_t R2_off   = R1_off + (size_t)N * sizeof(float);
    const size_t need     = R2_off + (size_t)N * sizeof(float);

    const bool special = (D == 64 && H == 128 && DEG == 16 && K == 32 &&
                          (N % 16) == 0 && (E % 64) == 0 && ws_size >= need);
    if (special) {
        __bf16*        W1pt = (__bf16*)((char*)d_ws + w1_off);
        float*         qs   = (float*)((char*)d_ws + qs_off);
        int*           npp  = (int*)((char*)d_ws + np_off);
        float*         vv   = (float*)((char*)d_ws + vv_off);
        float*         b1p  = (float*)((char*)d_ws + b1p_off);
        float*         w2p  = (float*)((char*)d_ws + w2p_off);
        unsigned char* A1u  = (unsigned char*)d_ws + A1_off;
        unsigned char* A2q  = (unsigned char*)d_ws + A2_off;
        float*         R1   = (float*)((char*)d_ws + R1_off);
        float*         R2   = (float*)((char*)d_ws + R2_off);

        prep_kernel<<<64, 256, 0, stream>>>(W1, b1, W2, W1pt, b1p, w2p, vv,
                                            npp, qs);
        const int T2 = N / 16;
        const int pblocks = (T2 + 3) / 4;          // 1 tile/wave, one-shot
        precomp_kernel<<<pblocks, 256, 0, stream>>>(nf, b1p, w2p, W1pt, qs,
                                                    A1u, A2q, T2, 0);
        precomp_kernel<<<pblocks, 256, 0, stream>>>(nf, b1p, w2p, W1pt, qs,
                                                    A1u, A2q, T2, 1);
        rsum_kernel<<<512, 256, 0, stream>>>(nf, qs, vv, b2, R1, R2, T2);
        const int eblocks = (E + 255) / 256;       // 64 edges/wave, one-shot
        edge_kernel<<<eblocks, 256, 0, stream>>>(A1u, A2q, R1, R2, qs, npp,
                                                 src, dst, out, E, K, N);
    } else {
        __bf16* W1t = (__bf16*)((char*)d_ws + w1_off);
        prep_w1_kernel<<<(twoD * H + 255) / 256, 256, 0, stream>>>(W1, W1t);
        attack_kernel_f<<<2048, 256, 0, stream>>>(nf, b1, W2, b2, src, dst,
                                                  W1t, out, N, K, DEG);
    }
}

// Round 18
// 71.647 us; speedup vs baseline: 1.1675x; 1.1675x over previous
//
#include <hip/hip_runtime.h>
#include <hip/hip_bf16.h>

typedef __attribute__((ext_vector_type(8))) __bf16 bf16x8;
typedef __attribute__((ext_vector_type(4))) float f32x4;

#if __has_builtin(__builtin_amdgcn_sad_u8)
__device__ __forceinline__ unsigned sad8(unsigned a, unsigned b, unsigned acc) {
    return __builtin_amdgcn_sad_u8(a, b, acc);
}
#else
__device__ __forceinline__ unsigned sad8(unsigned a, unsigned b, unsigned acc) {
    #pragma unroll
    for (int i = 0; i < 4; ++i) {
        int xa = (a >> (8 * i)) & 255, xb = (b >> (8 * i)) & 255;
        acc += (unsigned)((xa > xb) ? (xa - xb) : (xb - xa));
    }
    return acc;
}
#endif

// ---------------------------------------------------------------------------
// prep (fallback path only): W1 [128 k][128 col] f32 -> W1t [col][k] bf16
// ---------------------------------------------------------------------------
__global__ void prep_w1_kernel(const float* __restrict__ W1,
                               __bf16* __restrict__ W1t) {
    int i = blockIdx.x * 256 + threadIdx.x;
    int c = i >> 7;
    int k = i & 127;
    W1t[i] = (__bf16)W1[k * 128 + c];
}

// ---------------------------------------------------------------------------
// Merged prep: every block recomputes the sign-sort permutation locally
// (plus-w2 columns first), then writes its slice of the permuted weights.
// MFMA column j = ct*16+cc <-> rank p = cc*8+ct; H-col c = perm_inv[p].
// i==0 thread emits qs/np. (No flag: edge self-checks dst per wave.)
// ---------------------------------------------------------------------------
__global__ void prep_kernel(const float* __restrict__ W1,
                            const float* __restrict__ b1,
                            const float* __restrict__ W2,
                            __bf16* __restrict__ W1pt,
                            float* __restrict__ b1p,
                            float* __restrict__ w2p,
                            int* __restrict__ npout,
                            float* __restrict__ qs) {
    __shared__ int perm_inv_s[128];
    __shared__ int wcnt[2];
    __shared__ float wmax[2];
    const int tid  = threadIdx.x;
    const int lane = tid & 63;
    const int w    = tid >> 6;
    bool pos = false;
    int rank = 0;
    if (tid < 128) {
        const float w2 = W2[tid];
        pos = (w2 > 0.f);
        unsigned long long bal = __ballot(pos);
        rank = __popcll(bal & ((1ull << lane) - 1ull));
        int cnt = __popcll(bal);
        float m = __builtin_fabsf(w2);
        #pragma unroll
        for (int d = 1; d < 64; d <<= 1) m = fmaxf(m, __shfl_xor(m, d, 64));
        if (lane == 0) { wcnt[w] = cnt; wmax[w] = m; }
    }
    __syncthreads();
    if (tid < 128) {
        const int npv   = wcnt[0] + wcnt[1];
        const int basep = (w == 1) ? wcnt[0] : 0;
        const int negb  = (w == 1) ? (64 - wcnt[0]) : 0;
        const int p = pos ? (basep + rank) : (npv + negb + (lane - rank));
        perm_inv_s[p] = tid;
    }
    __syncthreads();

    const int i = blockIdx.x * 256 + tid;     // 64 blocks x 256 = 16384
    const int j = i >> 7;
    const int k = i & 127;
    const int c = perm_inv_s[(j & 15) * 8 + (j >> 4)];
    W1pt[i] = (__bf16)W1[k * 128 + c];
    if (k == 0) { b1p[j] = b1[c]; w2p[j] = W2[c]; }
    if (i == 0) {
        float mm = fmaxf(wmax[0], wmax[1]);
        float s  = (mm > 0.f) ? (6.0f * mm / 120.0f) : 1.0f;
        qs[0] = 1.0f / s;
        qs[1] = 0.495f * s;
        *npout = wcnt[0] + wcnt[1];
    }
}

// ---------------------------------------------------------------------------
// Fused precompute — the measured-fast configuration (r11/r16, 44-47us):
//   rawA = nf@W1[0:64]+b1 -> A1u u8 (128 B/row, TRANSPOSED byte order:
//          byte j holds rank 16*(j>>4) + 4*(j&3) + ((j>>2)&3)), R1
//   rawB = nf@W1[64:128]  -> A2q 2-bit (32 B/row; lane cc stores ushort with
//          rank cc*8+ct at bits 2*ct), R2
// A1 transpose via one shfl_xor(1) halfword swap per dword; contiguous int2
// stores. nf loads issued first (HBM long pole). One wave per 16-node tile.
// ---------------------------------------------------------------------------
__global__ __launch_bounds__(256, 2) void precomp_kernel(
                               const float* __restrict__ nf,
                               const float* __restrict__ b1p,
                               const float* __restrict__ w2p,
                               const float* __restrict__ b2,
                               const __bf16* __restrict__ W1pt,
                               const float* __restrict__ qs,
                               unsigned char* __restrict__ A1u,
                               unsigned char* __restrict__ A2q,
                               float* __restrict__ R1,
                               float* __restrict__ R2,
                               int T2) {
    const int lane = threadIdx.x & 63;
    const int wid  = threadIdx.x >> 6;
    const int cc   = lane & 15;
    const int kg   = lane >> 4;
    const int g    = blockIdx.x * 4 + wid;
    if (g >= T2) return;

    // ---- nf loads first: the HBM long pole ----
    const float* ap = nf + ((long)g * 16 + cc) * 64 + kg * 8;
    f32x4 lo0 = *(const f32x4*)(ap);
    f32x4 hi0 = *(const f32x4*)(ap + 4);
    f32x4 lo1 = *(const f32x4*)(ap + 32);
    f32x4 hi1 = *(const f32x4*)(ap + 36);

    const float inv_s = qs[0];
    float bw[8], wv[8], m8[8], m85[8];
    #pragma unroll
    for (int ct = 0; ct < 8; ++ct) {
        const int col = ct * 16 + cc;
        const float w2v = w2p[col];
        bw[ct]  = b1p[col];
        wv[ct]  = w2v;
        m8[ct]  = inv_s * __builtin_fabsf(w2v);
        m85[ct] = m8[ct] * (1.0f / 85.0f);
    }
    const float b2v = b2[0];

    bf16x8 a0, a1;
    #pragma unroll
    for (int j = 0; j < 4; ++j) {
        a0[j] = (__bf16)lo0[j]; a0[4 + j] = (__bf16)hi0[j];
        a1[j] = (__bf16)lo1[j]; a1[4 + j] = (__bf16)hi1[j];
    }

    f32x4 accB[8];
    #pragma unroll
    for (int ct = 0; ct < 8; ++ct) {
        const __bf16* colp = W1pt + (ct * 16 + cc) * 128 + 64 + kg * 8;
        bf16x8 bf0 = *(const bf16x8*)(colp);
        bf16x8 bf1 = *(const bf16x8*)(colp + 32);
        f32x4 acc = (f32x4){0.f, 0.f, 0.f, 0.f};
        acc = __builtin_amdgcn_mfma_f32_16x16x32_bf16(a0, bf0, acc, 0, 0, 0);
        acc = __builtin_amdgcn_mfma_f32_16x16x32_bf16(a1, bf1, acc, 0, 0, 0);
        accB[ct] = acc;
    }
    f32x4 accA[8];
    #pragma unroll
    for (int ct = 0; ct < 8; ++ct) {
        const __bf16* colp = W1pt + (ct * 16 + cc) * 128 + kg * 8;
        bf16x8 bf0 = *(const bf16x8*)(colp);
        bf16x8 bf1 = *(const bf16x8*)(colp + 32);
        f32x4 acc = (f32x4){0.f, 0.f, 0.f, 0.f};
        acc = __builtin_amdgcn_mfma_f32_16x16x32_bf16(a0, bf0, acc, 0, 0, 0);
        acc = __builtin_amdgcn_mfma_f32_16x16x32_bf16(a1, bf1, acc, 0, 0, 0);
        accA[ct] = acc;
    }

    #pragma unroll
    for (int r = 0; r < 4; ++r) {
        const long n = (long)g * 16 + kg * 4 + r;
        float rs1 = 0.f, rs2 = 0.f;
        unsigned ub[8];
        unsigned pk16 = 0;
        #pragma unroll
        for (int ct = 0; ct < 8; ++ct) {
            const float rawA = accA[ct][r] + bw[ct];
            const float rawB = accB[ct][r];
            rs1 = fmaf(rawA, wv[ct], rs1);
            rs2 = fmaf(rawB, wv[ct], rs2);
            float xA = fmaf(rawA, m8[ct], 128.f);
            xA = fminf(fmaxf(xA, 1.f), 254.f);
            ub[ct] = (unsigned)(xA + 0.5f);
            // 2-bit code: floor(2.00588 - rawB*m85), clamped to [0,3]
            float tB = fmaf(rawB, -m85[ct], 2.00588f);
            tB = fminf(fmaxf(tB, 0.f), 3.0f);
            pk16 |= ((unsigned)tB) << (2 * ct);
        }
        rs1 += __shfl_xor(rs1, 1, 64);
        rs1 += __shfl_xor(rs1, 2, 64);
        rs1 += __shfl_xor(rs1, 4, 64);
        rs1 += __shfl_xor(rs1, 8, 64);
        rs2 += __shfl_xor(rs2, 1, 64);
        rs2 += __shfl_xor(rs2, 2, 64);
        rs2 += __shfl_xor(rs2, 4, 64);
        rs2 += __shfl_xor(rs2, 8, 64);

        // A1 transposed pack: dword k of 16-byte block (cc>>1) =
        //   even.ub[k] | even.ub[k+4]<<8 | odd.ub[k]<<16 | odd.ub[k+4]<<24
        unsigned half_[4], dw[4];
        #pragma unroll
        for (int k = 0; k < 4; ++k) half_[k] = ub[k] | (ub[k + 4] << 8);
        const bool oddl = (cc & 1);
        #pragma unroll
        for (int k = 0; k < 4; ++k) {
            unsigned ph = (unsigned)__shfl_xor((int)half_[k], 1, 64);
            dw[k] = oddl ? (ph | (half_[k] << 16)) : (half_[k] | (ph << 16));
        }
        int2 st;
        st.x = (int)(oddl ? dw[2] : dw[0]);
        st.y = (int)(oddl ? dw[3] : dw[1]);
        *(int2*)(A1u + n * 128 + cc * 8) = st;
        *(unsigned short*)(A2q + n * 32 + cc * 2) = (unsigned short)pk16;
        if (cc == 0) {
            R1[n] = 0.505f * rs1 + b2v;
            R2[n] = 0.505f * rs2;
        }
    }
}

// ---------------------------------------------------------------------------
// Edge pass, one edge per lane, one-shot wave (~21us, stable r10-r16).
// Per-wave dst self-check (coalesced load + ballot): canonical pattern ->
// dv=e>>4, slot=e&15, writes score + filler. Slow path (any sorted dst):
// binary-search slot; firstseg/lastseg/tail lanes write remaining fillers.
//   A2 row: 2 int4 (32 B, 3.2 MB table -> per-XCD L2-resident)
//   plane k of dword d: x=(v>>2k)&0x03030303, y=x*85 -> A1 dword 4d+k
//   (transposed A1: byte b of dword 4d+k holds rank 16d+4b+k).
//   masks: dword m=4d+k, byte b on iff rank 16d+4b+k < np.
//   score = R1[dv] + R2[se] + 0.495*s*(2*S_plus - S_all)
// ---------------------------------------------------------------------------
__global__ __launch_bounds__(256, 2) void edge_kernel(
                            const unsigned char* __restrict__ A1u,
                            const unsigned char* __restrict__ A2q,
                            const float* __restrict__ R1,
                            const float* __restrict__ R2,
                            const float* __restrict__ qs,
                            const int* __restrict__ npp,
                            const int* __restrict__ src,
                            const int* __restrict__ dst,
                            float* __restrict__ out,
                            int E, int K, int N) {
    const int lane = threadIdx.x & 63;
    const int gw   = blockIdx.x * 4 + (threadIdx.x >> 6);
    const float k0 = qs[1];
    const int np   = *npp;

    // mask dword m=4d+k: byte b on iff rank 16d+4b+k < np  (wave-uniform)
    unsigned M[32];
    #pragma unroll
    for (int m = 0; m < 32; ++m) {
        const int d = m >> 2, k = m & 3;
        const int t = np - 16 * d - k;
        int bc = (t <= 0) ? 0 : ((t + 3) >> 2);
        bc = bc > 4 ? 4 : bc;
        M[m] = (bc >= 4) ? 0xFFFFFFFFu
             : ((bc <= 0) ? 0u : (0xFFFFFFFFu >> (8 * (4 - bc))));
    }

    const int e = gw * 64 + lane;
    const bool act = (e < E);
    const int dvl = act ? dst[e] : 0;
    const bool okc = !act || (dvl == (e >> 4));
    const bool fast = (__ballot(okc) == ~0ull);
    if (!act) return;

    int dv, slot;
    bool firstseg = false, lastseg = false;
    if (fast) { dv = e >> 4; slot = e & 15; }
    else {
        dv = dvl;
        int lo = 0, hi = e;
        while (lo < hi) {
            int mid = (lo + hi) >> 1;
            if (dst[mid] < dv) lo = mid + 1; else hi = mid;
        }
        slot = e - lo;
        firstseg = (e == 0) || (dst[e - 1] != dv);
        lastseg  = (e + 1 >= E) || (dst[e + 1] != dv);
    }
    const int se = src[e];

    const unsigned char* bp = A2q + (long)se * 32;
    int4 q0 = *(const int4*)(bp);
    int4 q1 = *(const int4*)(bp + 16);
    const unsigned char* ap_ = A1u + (long)dv * 128;
    unsigned A[32];
    #pragma unroll
    for (int i = 0; i < 8; ++i) {
        int4 t = *(const int4*)(ap_ + i * 16);
        A[4 * i]     = (unsigned)t.x;
        A[4 * i + 1] = (unsigned)t.y;
        A[4 * i + 2] = (unsigned)t.z;
        A[4 * i + 3] = (unsigned)t.w;
    }
    const float r12 = R1[dv] + R2[se];

    unsigned B[8] = {(unsigned)q0.x, (unsigned)q0.y, (unsigned)q0.z, (unsigned)q0.w,
                     (unsigned)q1.x, (unsigned)q1.y, (unsigned)q1.z, (unsigned)q1.w};
    unsigned sall = 0, spl = 0;
    #pragma unroll
    for (int d = 0; d < 8; ++d) {
        const unsigned v = B[d];
        #pragma unroll
        for (int k = 0; k < 4; ++k) {
            unsigned x = (v >> (2 * k)) & 0x03030303u;
            unsigned y = x + (x << 2);     // x*5
            y = y + (y << 4);              // x*85  (no cross-byte carries)
            const unsigned mm = M[4 * d + k];
            const unsigned aa = A[4 * d + k];
            sall = sad8(aa, y, sall);
            spl  = sad8(aa & mm, y & mm, spl);
        }
    }

    const float score = fmaf(k0, 2.0f * (float)spl - (float)sall, r12);
    float* orow = out + (long)dv * K;
    if (fast) {
        orow[slot]      = score;
        orow[16 + slot] = -1e10f;
    } else {
        if (slot < K) orow[slot] = score;
        if (lastseg)
            for (int q = (slot + 1 < 0 ? 0 : slot + 1); q < K; ++q)
                orow[q] = -1e10f;
        if (firstseg) {
            const int prev = (e == 0) ? -1 : dst[e - 1];
            for (long nn = prev + 1; nn < dv; ++nn)
                for (int q = 0; q < K; ++q) out[nn * K + q] = -1e10f;
        }
        if (e == E - 1)
            for (long nn = (long)dv + 1; nn < N; ++nn)
                for (int q = 0; q < K; ++q) out[nn * K + q] = -1e10f;
    }
}

// ---------------------------------------------------------------------------
// Fallback (round-1 kernel) for non-special shapes / tiny ws.
// ---------------------------------------------------------------------------
__global__ void attack_kernel_f(
    const float* __restrict__ nf, const float* __restrict__ b1,
    const float* __restrict__ W2, const float* __restrict__ b2,
    const int* __restrict__ src, const int* __restrict__ dst,
    const __bf16* __restrict__ W1t, float* __restrict__ out,
    int T, int K, int DEG)
{
    const int lane = threadIdx.x & 63;
    const int wid  = threadIdx.x >> 6;
    const int row  = lane & 15;
    const int kg   = lane >> 4;

    bf16x8 bfrag[8][4];
    #pragma unroll
    for (int ct = 0; ct < 8; ++ct) {
        const __bf16* colp = W1t + (ct * 16 + row) * 128 + kg * 8;
        #pragma unroll
        for (int kk = 0; kk < 4; ++kk)
            bfrag[ct][kk] = *(const bf16x8*)(colp + kk * 32);
    }
    float b1c[8], w2c[8];
    #pragma unroll
    for (int ct = 0; ct < 8; ++ct) {
        b1c[ct] = b1[ct * 16 + row];
        w2c[ct] = W2[ct * 16 + row];
    }
    const float b2v = b2[0];

    const int wstride = gridDim.x * 4;
    for (int t = blockIdx.x * 4 + wid; t < T; t += wstride) {
        const long eb = (long)t * DEG;
        const int dv = dst[eb];
        const int sv = src[eb + row];
        bf16x8 afrag[4];
        const float* dp = nf + (long)dv * 64 + kg * 8;
        const float* sp = nf + (long)sv * 64 + kg * 8;
        #pragma unroll
        for (int kk = 0; kk < 2; ++kk) {
            f32x4 lo = *(const f32x4*)(dp + kk * 32);
            f32x4 hi = *(const f32x4*)(dp + kk * 32 + 4);
            bf16x8 a;
            #pragma unroll
            for (int j = 0; j < 4; ++j) { a[j] = (__bf16)lo[j]; a[4 + j] = (__bf16)hi[j]; }
            afrag[kk] = a;
        }
        #pragma unroll
        for (int kk = 0; kk < 2; ++kk) {
            f32x4 lo = *(const f32x4*)(sp + kk * 32);
            f32x4 hi = *(const f32x4*)(sp + kk * 32 + 4);
            bf16x8 a;
            #pragma unroll
            for (int j = 0; j < 4; ++j) { a[j] = (__bf16)lo[j]; a[4 + j] = (__bf16)hi[j]; }
            afrag[2 + kk] = a;
        }
        f32x4 acc[8];
        #pragma unroll
        for (int ct = 0; ct < 8; ++ct) acc[ct] = (f32x4){0.f, 0.f, 0.f, 0.f};
        #pragma unroll
        for (int ct = 0; ct < 8; ++ct) {
            #pragma unroll
            for (int kk = 0; kk < 4; ++kk)
                acc[ct] = __builtin_amdgcn_mfma_f32_16x16x32_bf16(
                    afrag[kk], bfrag[ct][kk], acc[ct], 0, 0, 0);
        }
        float part[4] = {0.f, 0.f, 0.f, 0.f};
        #pragma unroll
        for (int ct = 0; ct < 8; ++ct) {
            #pragma unroll
            for (int r = 0; r < 4; ++r) {
                float h = acc[ct][r] + b1c[ct];
                h = fmaxf(h, 0.01f * h);
                part[r] = fmaf(h, w2c[ct], part[r]);
            }
        }
        #pragma unroll
        for (int m = 1; m < 16; m <<= 1) {
            #pragma unroll
            for (int r = 0; r < 4; ++r)
                part[r] += __shfl_xor(part[r], m, 64);
        }
        float* orow = out + (long)dv * K;
        if (row == 0) {
            f32x4 v;
            #pragma unroll
            for (int r = 0; r < 4; ++r) v[r] = part[r] + b2v;
            *(f32x4*)(orow + kg * 4) = v;
            *(f32x4*)(orow + DEG + kg * 4) = (f32x4){-1e10f, -1e10f, -1e10f, -1e10f};
        }
    }
}

extern "C" void kernel_launch(void* const* d_in, const int* in_sizes, int n_in,
                              void* d_out, int out_size, void* d_ws, size_t ws_size,
                              hipStream_t stream) {
    const float* nf  = (const float*)d_in[0];
    const float* W1  = (const float*)d_in[1];
    const float* b1  = (const float*)d_in[2];
    const float* W2  = (const float*)d_in[3];
    const float* b2  = (const float*)d_in[4];
    const int*   src = (const int*)d_in[5];
    const int*   dst = (const int*)d_in[6];
    float* out = (float*)d_out;

    const int H    = in_sizes[2];          // 128
    const int twoD = in_sizes[1] / H;      // 128
    const int D    = twoD / 2;             // 64
    const int N    = in_sizes[0] / D;      // 100000
    const int E    = in_sizes[5];          // 1600000
    const int DEG  = E / N;                // 16
    const int K    = out_size / N;         // 32

    // ws layout
    const size_t w1_off   = 0;                 // 32 KiB (W1pt or W1t)
    const size_t qs_off   = 32768;             // 16 B
    const size_t np_off   = 32784;             // 4 B
    const size_t b1p_off  = 33312;             // 512 B
    const size_t w2p_off  = 33824;             // 512 B
    const size_t A1_off   = 34560;             // 256-aligned
    const size_t A1_sz    = (size_t)N * 128;   // u8 table (12.8 MB)
    const size_t A2_off   = A1_off + A1_sz;
    const size_t A2_sz    = (size_t)N * 32;    // 2-bit table (3.2 MB)
    const size_t R1_off   = A2_off + A2_sz;
    const size_t R2_off   = R1_off + (size_t)N * sizeof(float);
    const size_t need     = R2_off + (size_t)N * sizeof(float);

    const bool special = (D == 64 && H == 128 && DEG == 16 && K == 32 &&
                          (N % 16) == 0 && (E % 64) == 0 && ws_size >= need);
    if (special) {
        __bf16*        W1pt = (__bf16*)((char*)d_ws + w1_off);
        float*         qs   = (float*)((char*)d_ws + qs_off);
        int*           npp  = (int*)((char*)d_ws + np_off);
        float*         b1p  = (float*)((char*)d_ws + b1p_off);
        float*         w2p  = (float*)((char*)d_ws + w2p_off);
        unsigned char* A1u  = (unsigned char*)d_ws + A1_off;
        unsigned char* A2q  = (unsigned char*)d_ws + A2_off;
        float*         R1   = (float*)((char*)d_ws + R1_off);
        float*         R2   = (float*)((char*)d_ws + R2_off);

        prep_kernel<<<64, 256, 0, stream>>>(W1, b1, W2, W1pt, b1p, w2p,
                                            npp, qs);
        const int T2 = N / 16;
        const int pblocks = (T2 + 3) / 4;          // 1 tile per wave, one-shot
        precomp_kernel<<<pblocks, 256, 0, stream>>>(nf, b1p, w2p, b2, W1pt, qs,
                                                    A1u, A2q, R1, R2, T2);
        const int eblocks = (E + 255) / 256;       // 64 edges/wave, one-shot
        edge_kernel<<<eblocks, 256, 0, stream>>>(A1u, A2q, R1, R2, qs, npp,
                                                 src, dst, out, E, K, N);
    } else {
        __bf16* W1t = (__bf16*)((char*)d_ws + w1_off);
        prep_w1_kernel<<<(twoD * H + 255) / 256, 256, 0, stream>>>(W1, W1t);
        attack_kernel_f<<<2048, 256, 0, stream>>>(nf, b1, W2, b2, src, dst,
                                                  W1t, out, N, K, DEG);
    }
}